// Round 5
// baseline (4627.481 us; speedup 1.0000x reference)
//
#include <hip/hip_runtime.h>

// ---------------------------------------------------------------------------
// OneSideInterModalityUpdate (MI355X). Round 5: fp32 OUTPUT (the bug).
// Story: inputs fp32, dict order (in_sizes-verified, with sorted fallback);
// output buffer is fp32 (reference returns float32). Rounds 2-4 wrote bf16
// u16 into the fp32 buffer -> absmax 4.97 from pair-packing.
// Pipeline:
//   GEMM1: kv  = (src @ Ws^T + bs) * src_mask      [8192 x 2048] bf16 (ws)
//   GEMM2: q   = (tgt @ Wt^T + bt) * tgt_mask      [8192 x 1024] bf16 (ws)
//   ATTN : upd = softmax(q k^T / sqrt(128)) v       [8192 x 1024] bf16 (ws)
//   GEMM3: out = [tgt | upd] @ Wo^T + bo            [8192 x 1024] fp32 (d_out)
// ---------------------------------------------------------------------------

typedef __bf16 bf16x8 __attribute__((ext_vector_type(8)));
typedef float f32x4 __attribute__((ext_vector_type(4)));
typedef unsigned short u16;
typedef unsigned short u16x8 __attribute__((ext_vector_type(8)));

#define MFMA16(a, b, c) __builtin_amdgcn_mfma_f32_16x16x32_bf16((a), (b), (c), 0, 0, 0)

__device__ __forceinline__ float bf2f(u16 b) {
  return __uint_as_float(((unsigned)b) << 16);
}
__device__ __forceinline__ u16 f2bf(float f) {
  unsigned u = __float_as_uint(f);
  u += 0x7fffu + ((u >> 16) & 1u);  // RNE
  return (u16)(u >> 16);
}

__device__ __forceinline__ void store_out(u16* p, float v)   { *p = f2bf(v); }
__device__ __forceinline__ void store_out(float* p, float v) { *p = v; }

// ---------------------------------------------------------------------------
// C[m,n] = (sum_k A[m,k] B[n,k] + bias[n]) * rowscale[m]
// A: fp32 A0f (row stride splitK) for k<splitK, bf16 A1b (stride K-splitK) after.
// B: fp32, row-major [N][K]. Staging converts to bf16 in-register -> LDS.
// MFMA conventions (HW-verified, guide m89/m92/m97):
//   A-frag: lane l holds A[l%16][8*(l/16)+j]   B-frag: B[n=l%16][k=8*(l/16)+j]
//   D: row m = 4*(l/16)+r, col n = l%16
// ---------------------------------------------------------------------------
template <typename OutT>
__global__ __launch_bounds__(256, 2)
void gemm_bt_kernel(const float* __restrict__ A0f, const u16* __restrict__ A1b,
                    int splitK,
                    const float* __restrict__ Bw, const float* __restrict__ bias,
                    const float* __restrict__ rowscale,
                    OutT* __restrict__ C, int N, int K)
{
  __shared__ u16 As[128 * 32];
  __shared__ u16 Bs[128 * 32];
  const int tid  = threadIdx.x;
  const int lane = tid & 63;
  const int w    = tid >> 6;
  const int wm = w >> 1, wn = w & 1;
  const int quad = lane >> 4, lr = lane & 15;
  const int m0 = blockIdx.y * 128;
  const int n0 = blockIdx.x * 128;

  const f32x4 z4 = {0.f, 0.f, 0.f, 0.f};
  f32x4 acc[4][4];
#pragma unroll
  for (int i = 0; i < 4; ++i)
#pragma unroll
    for (int j = 0; j < 4; ++j)
      acc[i][j] = z4;

  for (int k0 = 0; k0 < K; k0 += 32) {
    __syncthreads();  // previous tile's reads done before overwrite
    if (k0 < splitK) {
#pragma unroll
      for (int rr = 0; rr < 4; ++rr) {
        const int row = rr * 32 + (tid >> 3);
        const int cq  = (tid & 7) * 4;
        const float4 a4 = *(const float4*)&A0f[(size_t)(m0 + row) * splitK + k0 + cq];
        ushort4 o;
        o.x = f2bf(a4.x); o.y = f2bf(a4.y); o.z = f2bf(a4.z); o.w = f2bf(a4.w);
        *(ushort4*)&As[row * 32 + cq] = o;
      }
    } else {
      const int kk = k0 - splitK, lda = K - splitK;
#pragma unroll
      for (int rr = 0; rr < 2; ++rr) {
        const int row = rr * 64 + (tid >> 2);
        const int cc  = (tid & 3) * 8;
        *(u16x8*)&As[row * 32 + cc] =
            *(const u16x8*)&A1b[(size_t)(m0 + row) * lda + kk + cc];
      }
    }
#pragma unroll
    for (int rr = 0; rr < 4; ++rr) {
      const int row = rr * 32 + (tid >> 3);
      const int cq  = (tid & 7) * 4;
      const float4 b4 = *(const float4*)&Bw[(size_t)(n0 + row) * K + k0 + cq];
      ushort4 o;
      o.x = f2bf(b4.x); o.y = f2bf(b4.y); o.z = f2bf(b4.z); o.w = f2bf(b4.w);
      *(ushort4*)&Bs[row * 32 + cq] = o;
    }
    __syncthreads();  // staging visible

    bf16x8 af[4], bfr[4];
#pragma unroll
    for (int i = 0; i < 4; ++i)
      af[i] = *(const bf16x8*)&As[(wm * 64 + i * 16 + lr) * 32 + quad * 8];
#pragma unroll
    for (int j = 0; j < 4; ++j)
      bfr[j] = *(const bf16x8*)&Bs[(wn * 64 + j * 16 + lr) * 32 + quad * 8];
#pragma unroll
    for (int i = 0; i < 4; ++i)
#pragma unroll
      for (int j = 0; j < 4; ++j)
        acc[i][j] = MFMA16(af[i], bfr[j], acc[i][j]);
  }

  float bv[4];
#pragma unroll
  for (int j = 0; j < 4; ++j)
    bv[j] = bias[n0 + wn * 64 + j * 16 + lr];

#pragma unroll
  for (int i = 0; i < 4; ++i)
#pragma unroll
    for (int r = 0; r < 4; ++r) {
      const int grow = m0 + wm * 64 + i * 16 + quad * 4 + r;
      float rs = 1.f;
      if (rowscale) rs = rowscale[grow];
#pragma unroll
      for (int j = 0; j < 4; ++j) {
        const int gcol = n0 + wn * 64 + j * 16 + lr;
        store_out(&C[(size_t)grow * N + gcol], (acc[i][j][r] + bv[j]) * rs);
      }
    }
}

// ---------------------------------------------------------------------------
// Naive attention: one wave per (b,h,t). Lane l owns d = {2l, 2l+1}.
// ---------------------------------------------------------------------------
#define SCLOG2E 0.12751813754618667f  // (1/sqrt(128)) * log2(e)

__global__ __launch_bounds__(256)
void attn_naive_kernel(const u16* __restrict__ q, const u16* __restrict__ kv,
                       const float* __restrict__ smask, u16* __restrict__ upd)
{
  const int tid = threadIdx.x, lane = tid & 63, w = tid >> 6;
  const int b = blockIdx.z, h = blockIdx.y;
  const int t = blockIdx.x * 4 + w;

  const size_t qoff = ((size_t)b * 1024 + t) * 1024 + h * 128 + lane * 2;
  const unsigned qp = *(const unsigned*)&q[qoff];
  const float q0 = bf2f((u16)(qp & 0xffff)), q1 = bf2f((u16)(qp >> 16));

  const u16* kbase = kv + (size_t)b * 1024 * 2048 + h * 128 + lane * 2;
  const float* mbase = smask + b * 1024;

  float m = -1e30f, l = 0.f, o0 = 0.f, o1 = 0.f;
  for (int s = 0; s < 1024; ++s) {
    const unsigned kp = *(const unsigned*)&kbase[(size_t)s * 2048];
    float part = q0 * bf2f((u16)(kp & 0xffff)) + q1 * bf2f((u16)(kp >> 16));
    part += __shfl_xor(part, 1);
    part += __shfl_xor(part, 2);
    part += __shfl_xor(part, 4);
    part += __shfl_xor(part, 8);
    part += __shfl_xor(part, 16);
    part += __shfl_xor(part, 32);
    float sc = part * SCLOG2E;
    const bool live = (mbase[s] != 0.f);
    const float scm = live ? sc : -1e30f;
    const float mnew = fmaxf(m, scm);
    const float alpha = exp2f(m - mnew);
    const float p = live ? exp2f(sc - mnew) : 0.f;
    const unsigned vp = *(const unsigned*)&kbase[(size_t)s * 2048 + 1024];
    const float v0 = bf2f((u16)(vp & 0xffff)), v1 = bf2f((u16)(vp >> 16));
    l  = l  * alpha + p;
    o0 = o0 * alpha + p * v0;
    o1 = o1 * alpha + p * v1;
    m = mnew;
  }
  const float inv = 1.f / l;
  upd[qoff]     = f2bf(o0 * inv);
  upd[qoff + 1] = f2bf(o1 * inv);
}

// diagnostic: mark out[0] with a magic value (fp32 -> observable)
__global__ void magic_kernel(float* out, float val)
{
  if (threadIdx.x == 0 && blockIdx.x == 0) out[0] = val;
}

// ---------------------------------------------------------------------------
extern "C" void kernel_launch(void* const* d_in, const int* in_sizes, int n_in,
                              void* d_out, int out_size, void* d_ws, size_t ws_size,
                              hipStream_t stream)
{
  static const int dict_sz[10]   = {8388608, 8388608, 8192, 8192, 2097152,
                                    2048, 1048576, 1024, 2097152, 1024};
  static const int sorted_sz[10] = {2097152, 2097152, 1048576, 1024, 2048,
                                    1024, 8388608, 8192, 8388608, 8192};
  bool is_dict = (n_in == 10), is_sorted = (n_in == 10);
  if (n_in == 10) {
    for (int i = 0; i < 10; ++i) {
      if (in_sizes[i] != dict_sz[i])   is_dict = false;
      if (in_sizes[i] != sorted_sz[i]) is_sorted = false;
    }
  }

  const float *src, *tgt, *smask, *tmask, *Ws, *bs, *Wt, *bt, *Wo, *bo;
  if (is_sorted) {  // [Wo, Ws, Wt, bo, bs, bt, src, src_mask, tgt, tgt_mask]
    Wo    = (const float*)d_in[0];
    Ws    = (const float*)d_in[1];
    Wt    = (const float*)d_in[2];
    bo    = (const float*)d_in[3];
    bs    = (const float*)d_in[4];
    bt    = (const float*)d_in[5];
    src   = (const float*)d_in[6];
    smask = (const float*)d_in[7];
    tgt   = (const float*)d_in[8];
    tmask = (const float*)d_in[9];
  } else {  // dict order (documented contract)
    src   = (const float*)d_in[0];
    tgt   = (const float*)d_in[1];
    smask = (const float*)d_in[2];
    tmask = (const float*)d_in[3];
    Ws    = (const float*)d_in[4];
    bs    = (const float*)d_in[5];
    Wt    = (const float*)d_in[6];
    bt    = (const float*)d_in[7];
    Wo    = (const float*)d_in[8];
    bo    = (const float*)d_in[9];
  }
  float* out = (float*)d_out;  // fp32 output (reference returns float32)

  const size_t ws_needed = ((size_t)16777216 + 8388608 + 8388608) * 2;  // 64 MiB
  unsigned ws_mb = (unsigned)(ws_size >> 20);
  if (ws_mb > 999u) ws_mb = 999u;

  if (!is_dict && !is_sorted) {
    magic_kernel<<<dim3(1), dim3(64), 0, stream>>>(out, 4000.f + (float)ws_mb);
    return;
  }
  if (ws_size < ws_needed) {
    magic_kernel<<<dim3(1), dim3(64), 0, stream>>>(out, 3000.f + (float)ws_mb);
    return;
  }

  u16* kvbuf  = (u16*)d_ws;                   // [8192][2048]
  u16* qbuf   = kvbuf + (size_t)16777216;     // [8192][1024]
  u16* updbuf = qbuf  + (size_t)8388608;      // [8192][1024]

  dim3 blk(256);
  // GEMM1: kv = (src @ Ws^T + bs) * src_mask   (bf16 ws output)
  gemm_bt_kernel<u16><<<dim3(16, 64), blk, 0, stream>>>(
      src, nullptr, 1024, Ws, bs, smask, kvbuf, 2048, 1024);
  // GEMM2: q = (tgt @ Wt^T + bt) * tgt_mask    (bf16 ws output)
  gemm_bt_kernel<u16><<<dim3(8, 64), blk, 0, stream>>>(
      tgt, nullptr, 1024, Wt, bt, tmask, qbuf, 1024, 1024);
  // ATTN (naive): upd = softmax(q k^T) v       (bf16 ws output)
  attn_naive_kernel<<<dim3(256, 8, 8), blk, 0, stream>>>(qbuf, kvbuf, smask, updbuf);
  // GEMM3: out = [tgt | upd] @ Wo^T + bo       (fp32 output!)
  gemm_bt_kernel<float><<<dim3(8, 64), blk, 0, stream>>>(
      tgt, updbuf, 1024, Wo, bo, nullptr, out, 1024, 2048);
}

// Round 6
// 647.689 us; speedup vs baseline: 7.1446x; 7.1446x over previous
//
#include <hip/hip_runtime.h>

// ---------------------------------------------------------------------------
// OneSideInterModalityUpdate (MI355X). Round 6: MFMA flash attention replaces
// the naive VALU-bound attention (was 4950 us, VALUBusy 99%, MfmaUtil 0).
// Everything else byte-identical to the passing round-5 version.
// Pipeline:
//   GEMM1: kv  = (src @ Ws^T + bs) * src_mask      [8192 x 2048] bf16 (ws)
//   GEMM2: q   = (tgt @ Wt^T + bt) * tgt_mask      [8192 x 1024] bf16 (ws)
//   FLASH: upd = softmax(q k^T / sqrt(128)) v       [8192 x 1024] bf16 (ws)
//   GEMM3: out = [tgt | upd] @ Wo^T + bo            [8192 x 1024] fp32 (d_out)
// ---------------------------------------------------------------------------

typedef __bf16 bf16x8 __attribute__((ext_vector_type(8)));
typedef float f32x4 __attribute__((ext_vector_type(4)));
typedef unsigned short u16;
typedef unsigned short u16x8 __attribute__((ext_vector_type(8)));

#define MFMA16(a, b, c) __builtin_amdgcn_mfma_f32_16x16x32_bf16((a), (b), (c), 0, 0, 0)

__device__ __forceinline__ float bf2f(u16 b) {
  return __uint_as_float(((unsigned)b) << 16);
}
__device__ __forceinline__ u16 f2bf(float f) {
  unsigned u = __float_as_uint(f);
  u += 0x7fffu + ((u >> 16) & 1u);  // RNE
  return (u16)(u >> 16);
}

__device__ __forceinline__ void store_out(u16* p, float v)   { *p = f2bf(v); }
__device__ __forceinline__ void store_out(float* p, float v) { *p = v; }

// async global->LDS, 16B per lane; lds dest must be wave-uniform base + lane*16
__device__ __forceinline__ void async16(const u16* g, u16* l) {
  __builtin_amdgcn_global_load_lds(
      (const __attribute__((address_space(1))) unsigned int*)g,
      (__attribute__((address_space(3))) unsigned int*)l, 16, 0, 0);
}

// ---------------------------------------------------------------------------
// C[m,n] = (sum_k A[m,k] B[n,k] + bias[n]) * rowscale[m]
// A: fp32 A0f (row stride splitK) for k<splitK, bf16 A1b (stride K-splitK) after.
// B: fp32, row-major [N][K]. Staging converts to bf16 in-register -> LDS.
// MFMA conventions (HW-verified, guide m89/m92/m97):
//   A-frag: lane l holds A[l%16][8*(l/16)+j]   B-frag: B[n=l%16][k=8*(l/16)+j]
//   D: row m = 4*(l/16)+r, col n = l%16
// ---------------------------------------------------------------------------
template <typename OutT>
__global__ __launch_bounds__(256, 2)
void gemm_bt_kernel(const float* __restrict__ A0f, const u16* __restrict__ A1b,
                    int splitK,
                    const float* __restrict__ Bw, const float* __restrict__ bias,
                    const float* __restrict__ rowscale,
                    OutT* __restrict__ C, int N, int K)
{
  __shared__ u16 As[128 * 32];
  __shared__ u16 Bs[128 * 32];
  const int tid  = threadIdx.x;
  const int lane = tid & 63;
  const int w    = tid >> 6;
  const int wm = w >> 1, wn = w & 1;
  const int quad = lane >> 4, lr = lane & 15;
  const int m0 = blockIdx.y * 128;
  const int n0 = blockIdx.x * 128;

  const f32x4 z4 = {0.f, 0.f, 0.f, 0.f};
  f32x4 acc[4][4];
#pragma unroll
  for (int i = 0; i < 4; ++i)
#pragma unroll
    for (int j = 0; j < 4; ++j)
      acc[i][j] = z4;

  for (int k0 = 0; k0 < K; k0 += 32) {
    __syncthreads();  // previous tile's reads done before overwrite
    if (k0 < splitK) {
#pragma unroll
      for (int rr = 0; rr < 4; ++rr) {
        const int row = rr * 32 + (tid >> 3);
        const int cq  = (tid & 7) * 4;
        const float4 a4 = *(const float4*)&A0f[(size_t)(m0 + row) * splitK + k0 + cq];
        ushort4 o;
        o.x = f2bf(a4.x); o.y = f2bf(a4.y); o.z = f2bf(a4.z); o.w = f2bf(a4.w);
        *(ushort4*)&As[row * 32 + cq] = o;
      }
    } else {
      const int kk = k0 - splitK, lda = K - splitK;
#pragma unroll
      for (int rr = 0; rr < 2; ++rr) {
        const int row = rr * 64 + (tid >> 2);
        const int cc  = (tid & 3) * 8;
        *(u16x8*)&As[row * 32 + cc] =
            *(const u16x8*)&A1b[(size_t)(m0 + row) * lda + kk + cc];
      }
    }
#pragma unroll
    for (int rr = 0; rr < 4; ++rr) {
      const int row = rr * 32 + (tid >> 3);
      const int cq  = (tid & 7) * 4;
      const float4 b4 = *(const float4*)&Bw[(size_t)(n0 + row) * K + k0 + cq];
      ushort4 o;
      o.x = f2bf(b4.x); o.y = f2bf(b4.y); o.z = f2bf(b4.z); o.w = f2bf(b4.w);
      *(ushort4*)&Bs[row * 32 + cq] = o;
    }
    __syncthreads();  // staging visible

    bf16x8 af[4], bfr[4];
#pragma unroll
    for (int i = 0; i < 4; ++i)
      af[i] = *(const bf16x8*)&As[(wm * 64 + i * 16 + lr) * 32 + quad * 8];
#pragma unroll
    for (int j = 0; j < 4; ++j)
      bfr[j] = *(const bf16x8*)&Bs[(wn * 64 + j * 16 + lr) * 32 + quad * 8];
#pragma unroll
    for (int i = 0; i < 4; ++i)
#pragma unroll
      for (int j = 0; j < 4; ++j)
        acc[i][j] = MFMA16(af[i], bfr[j], acc[i][j]);
  }

  float bv[4];
#pragma unroll
  for (int j = 0; j < 4; ++j)
    bv[j] = bias[n0 + wn * 64 + j * 16 + lr];

#pragma unroll
  for (int i = 0; i < 4; ++i)
#pragma unroll
    for (int r = 0; r < 4; ++r) {
      const int grow = m0 + wm * 64 + i * 16 + quad * 4 + r;
      float rs = 1.f;
      if (rowscale) rs = rowscale[grow];
#pragma unroll
      for (int j = 0; j < 4; ++j) {
        const int gcol = n0 + wn * 64 + j * 16 + lr;
        store_out(&C[(size_t)grow * N + gcol], (acc[i][j][r] + bv[j]) * rs);
      }
    }
}

// ---------------------------------------------------------------------------
// MFMA flash attention. grid = (8 q-tiles, H=8, B=8); block = 256
// (4 waves x 32 q-rows). kv: [8192][2048] bf16 (k at h*128+d, v at
// 1024+h*128+d). q/upd: [8192][1024] bf16. K-tile = 64 keys.
// Ks chunk-permuted [dc16][s64][8] via global_load_lds; Vt[d][s+pad72] via
// register transpose; P via per-wave padded LDS (C-layout -> A-layout).
// ---------------------------------------------------------------------------
#define SCLOG2E 0.12751813754618667f  // (1/sqrt(128)) * log2(e)

__global__ __launch_bounds__(256, 2)
void flash_kernel(const u16* __restrict__ q, const u16* __restrict__ kv,
                  const float* __restrict__ smask, u16* __restrict__ upd)
{
  __shared__ u16 Ks[64 * 128];    // 16 KB
  __shared__ u16 Vt[128 * 72];    // 18 KB
  __shared__ u16 Ps[4][32 * 72];  // 18 KB

  const int tid  = threadIdx.x;
  const int lane = tid & 63;
  const int w    = tid >> 6;
  const int quad = lane >> 4, lr = lane & 15;
  const int b = blockIdx.z, h = blockIdx.y, qt = blockIdx.x;

  const size_t qrow0 = (size_t)b * 1024 + qt * 128 + w * 32;

  bf16x8 qf[2][4];  // A-layout: m=lane&15, k=quad*8+j
#pragma unroll
  for (int i = 0; i < 2; ++i)
#pragma unroll
    for (int kk = 0; kk < 4; ++kk)
      qf[i][kk] = *(const bf16x8*)&q[(qrow0 + i * 16 + lr) * 1024 + h * 128 + kk * 32 + quad * 8];

  const f32x4 z4 = {0.f, 0.f, 0.f, 0.f};
  f32x4 oacc[2][8];
#pragma unroll
  for (int i = 0; i < 2; ++i)
#pragma unroll
    for (int jd = 0; jd < 8; ++jd)
      oacc[i][jd] = z4;
  float mrun[2][4], lrun[2][4];
#pragma unroll
  for (int i = 0; i < 2; ++i)
#pragma unroll
    for (int r = 0; r < 4; ++r) { mrun[i][r] = -1e30f; lrun[i][r] = 0.f; }

  for (int s0 = 0; s0 < 1024; s0 += 64) {
    __syncthreads();
    // stage K: (it,w) handles dchunk dc=it*4+w, srow=lane -> Ks[dc*512+lane*8]
#pragma unroll
    for (int it = 0; it < 4; ++it) {
      const int f = it * 256 + tid;
      const int srow = f & 63, dc = f >> 6;
      async16(kv + ((size_t)b * 1024 + s0 + srow) * 2048 + h * 128 + dc * 8,
              &Ks[(it * 256 + (tid & 192)) * 8]);
    }
    // stage V transposed via registers: Vt[d][s], d = dc*8+jj
#pragma unroll
    for (int it = 0; it < 4; ++it) {
      const int f = it * 256 + tid;
      const int srow = f & 63, dc = f >> 6;
      u16x8 vv = *(const u16x8*)(kv + ((size_t)b * 1024 + s0 + srow) * 2048 + 1024 + h * 128 + dc * 8);
#pragma unroll
      for (int jj = 0; jj < 8; ++jj)
        Vt[(dc * 8 + jj) * 72 + srow] = vv[jj];
    }
    __syncthreads();

    // ---- S = Q K^T
    f32x4 sacc[2][4];
#pragma unroll
    for (int i = 0; i < 2; ++i)
#pragma unroll
      for (int j = 0; j < 4; ++j)
        sacc[i][j] = z4;
#pragma unroll
    for (int kk = 0; kk < 4; ++kk) {
      bf16x8 kb[4];
#pragma unroll
      for (int j = 0; j < 4; ++j)
        kb[j] = *(const bf16x8*)&Ks[((kk * 4 + quad) * 64 + j * 16 + lr) * 8];
#pragma unroll
      for (int i = 0; i < 2; ++i)
#pragma unroll
        for (int j = 0; j < 4; ++j)
          sacc[i][j] = MFMA16(qf[i][kk], kb[j], sacc[i][j]);
    }

    // ---- mask bias per key column (fp32 src_mask)
    float mb[4];
#pragma unroll
    for (int j = 0; j < 4; ++j) {
      const float mv = smask[b * 1024 + s0 + j * 16 + lr];
      mb[j] = (mv == 0.f) ? -1e30f : 0.f;
    }

    // ---- online softmax (row = 16-lane group within quad; shfl_xor 1/2/4/8)
#pragma unroll
    for (int i = 0; i < 2; ++i) {
      float alpha[4];
#pragma unroll
      for (int r = 0; r < 4; ++r) {
        float e[4];
#pragma unroll
        for (int j = 0; j < 4; ++j)
          e[j] = sacc[i][j][r] * SCLOG2E + mb[j];
        float vm = fmaxf(fmaxf(e[0], e[1]), fmaxf(e[2], e[3]));
        vm = fmaxf(vm, __shfl_xor(vm, 1));
        vm = fmaxf(vm, __shfl_xor(vm, 2));
        vm = fmaxf(vm, __shfl_xor(vm, 4));
        vm = fmaxf(vm, __shfl_xor(vm, 8));
        const float mnew = fmaxf(mrun[i][r], vm);
        alpha[r] = exp2f(mrun[i][r] - mnew);
        mrun[i][r] = mnew;
        float ps = 0.f;
#pragma unroll
        for (int j = 0; j < 4; ++j) {
          float p = exp2f(e[j] - mnew);
          ps += p;
          Ps[w][(i * 16 + quad * 4 + r) * 72 + j * 16 + lr] = f2bf(p);
        }
        ps += __shfl_xor(ps, 1);
        ps += __shfl_xor(ps, 2);
        ps += __shfl_xor(ps, 4);
        ps += __shfl_xor(ps, 8);
        lrun[i][r] = lrun[i][r] * alpha[r] + ps;
      }
#pragma unroll
      for (int jd = 0; jd < 8; ++jd)
#pragma unroll
        for (int r = 0; r < 4; ++r)
          oacc[i][jd][r] *= alpha[r];
    }

    // ---- O += P V
#pragma unroll
    for (int kk2 = 0; kk2 < 2; ++kk2) {
      bf16x8 pa[2], vb[8];
#pragma unroll
      for (int i = 0; i < 2; ++i)
        pa[i] = *(const bf16x8*)&Ps[w][(i * 16 + lr) * 72 + kk2 * 32 + quad * 8];
#pragma unroll
      for (int jd = 0; jd < 8; ++jd)
        vb[jd] = *(const bf16x8*)&Vt[(jd * 16 + lr) * 72 + kk2 * 32 + quad * 8];
#pragma unroll
      for (int i = 0; i < 2; ++i)
#pragma unroll
        for (int jd = 0; jd < 8; ++jd)
          oacc[i][jd] = MFMA16(pa[i], vb[jd], oacc[i][jd]);
    }
  }

#pragma unroll
  for (int i = 0; i < 2; ++i)
#pragma unroll
    for (int r = 0; r < 4; ++r) {
      const float inv = 1.f / lrun[i][r];
      const size_t grow = qrow0 + i * 16 + quad * 4 + r;
#pragma unroll
      for (int jd = 0; jd < 8; ++jd)
        upd[grow * 1024 + h * 128 + jd * 16 + lr] = f2bf(oacc[i][jd][r] * inv);
    }
}

// diagnostic: mark out[0] with a magic value (fp32 -> observable)
__global__ void magic_kernel(float* out, float val)
{
  if (threadIdx.x == 0 && blockIdx.x == 0) out[0] = val;
}

// ---------------------------------------------------------------------------
extern "C" void kernel_launch(void* const* d_in, const int* in_sizes, int n_in,
                              void* d_out, int out_size, void* d_ws, size_t ws_size,
                              hipStream_t stream)
{
  static const int dict_sz[10]   = {8388608, 8388608, 8192, 8192, 2097152,
                                    2048, 1048576, 1024, 2097152, 1024};
  static const int sorted_sz[10] = {2097152, 2097152, 1048576, 1024, 2048,
                                    1024, 8388608, 8192, 8388608, 8192};
  bool is_dict = (n_in == 10), is_sorted = (n_in == 10);
  if (n_in == 10) {
    for (int i = 0; i < 10; ++i) {
      if (in_sizes[i] != dict_sz[i])   is_dict = false;
      if (in_sizes[i] != sorted_sz[i]) is_sorted = false;
    }
  }

  const float *src, *tgt, *smask, *tmask, *Ws, *bs, *Wt, *bt, *Wo, *bo;
  if (is_sorted) {  // [Wo, Ws, Wt, bo, bs, bt, src, src_mask, tgt, tgt_mask]
    Wo    = (const float*)d_in[0];
    Ws    = (const float*)d_in[1];
    Wt    = (const float*)d_in[2];
    bo    = (const float*)d_in[3];
    bs    = (const float*)d_in[4];
    bt    = (const float*)d_in[5];
    src   = (const float*)d_in[6];
    smask = (const float*)d_in[7];
    tgt   = (const float*)d_in[8];
    tmask = (const float*)d_in[9];
  } else {  // dict order (documented contract)
    src   = (const float*)d_in[0];
    tgt   = (const float*)d_in[1];
    smask = (const float*)d_in[2];
    tmask = (const float*)d_in[3];
    Ws    = (const float*)d_in[4];
    bs    = (const float*)d_in[5];
    Wt    = (const float*)d_in[6];
    bt    = (const float*)d_in[7];
    Wo    = (const float*)d_in[8];
    bo    = (const float*)d_in[9];
  }
  float* out = (float*)d_out;  // fp32 output

  const size_t ws_needed = ((size_t)16777216 + 8388608 + 8388608) * 2;  // 64 MiB
  unsigned ws_mb = (unsigned)(ws_size >> 20);
  if (ws_mb > 999u) ws_mb = 999u;

  if (!is_dict && !is_sorted) {
    magic_kernel<<<dim3(1), dim3(64), 0, stream>>>(out, 4000.f + (float)ws_mb);
    return;
  }
  if (ws_size < ws_needed) {
    magic_kernel<<<dim3(1), dim3(64), 0, stream>>>(out, 3000.f + (float)ws_mb);
    return;
  }

  u16* kvbuf  = (u16*)d_ws;                   // [8192][2048]
  u16* qbuf   = kvbuf + (size_t)16777216;     // [8192][1024]
  u16* updbuf = qbuf  + (size_t)8388608;      // [8192][1024]

  dim3 blk(256);
  // GEMM1: kv = (src @ Ws^T + bs) * src_mask   (bf16 ws output)
  gemm_bt_kernel<u16><<<dim3(16, 64), blk, 0, stream>>>(
      src, nullptr, 1024, Ws, bs, smask, kvbuf, 2048, 1024);
  // GEMM2: q = (tgt @ Wt^T + bt) * tgt_mask    (bf16 ws output)
  gemm_bt_kernel<u16><<<dim3(8, 64), blk, 0, stream>>>(
      tgt, nullptr, 1024, Wt, bt, tmask, qbuf, 1024, 1024);
  // FLASH (MFMA): upd = softmax(q k^T) v       (bf16 ws output)
  flash_kernel<<<dim3(8, 8, 8), blk, 0, stream>>>(qbuf, kvbuf, smask, updbuf);
  // GEMM3: out = [tgt | upd] @ Wo^T + bo       (fp32 output)
  gemm_bt_kernel<float><<<dim3(8, 64), blk, 0, stream>>>(
      tgt, updbuf, 1024, Wo, bo, nullptr, out, 1024, 2048);
}

// Round 7
// 377.621 us; speedup vs baseline: 12.2543x; 1.7152x over previous
//
#include <hip/hip_runtime.h>

// ---------------------------------------------------------------------------
// OneSideInterModalityUpdate (MI355X). Round 7: async bf16 GEMMs.
// fp32->bf16 cvt pre-pass (src,tgt,Ws,Wt,Wo -> ws arena), then m97-style
// global_load_lds(16B) bf16 GEMMs (round-6 fp32-staged GEMMs were
// latency-bound: MfmaUtil 7%, VALUBusy 13%, Occ 24%). Flash unchanged.
// Pipeline:
//   CVT  : 5 fp32 tensors -> bf16 arena                 (~198 MB traffic)
//   GEMM1: kv  = (src @ Ws^T + bs) * src_mask      [8192 x 2048] bf16 (ws)
//   GEMM2: q   = (tgt @ Wt^T + bt) * tgt_mask      [8192 x 1024] bf16 (ws)
//   FLASH: upd = softmax(q k^T / sqrt(128)) v       [8192 x 1024] bf16 (ws)
//   GEMM3: out = [tgt | upd] @ Wo^T + bo            [8192 x 1024] fp32 (d_out)
// ---------------------------------------------------------------------------

typedef __bf16 bf16x8 __attribute__((ext_vector_type(8)));
typedef float f32x4 __attribute__((ext_vector_type(4)));
typedef unsigned short u16;
typedef unsigned short u16x8 __attribute__((ext_vector_type(8)));

#define MFMA16(a, b, c) __builtin_amdgcn_mfma_f32_16x16x32_bf16((a), (b), (c), 0, 0, 0)

__device__ __forceinline__ float bf2f(u16 b) {
  return __uint_as_float(((unsigned)b) << 16);
}
__device__ __forceinline__ u16 f2bf(float f) {
  unsigned u = __float_as_uint(f);
  u += 0x7fffu + ((u >> 16) & 1u);  // RNE
  return (u16)(u >> 16);
}

__device__ __forceinline__ void store_out(u16* p, float v)   { *p = f2bf(v); }
__device__ __forceinline__ void store_out(float* p, float v) { *p = v; }

// async global->LDS, 16B per lane; lds dest = wave-uniform base + lane*16
__device__ __forceinline__ void async16(const u16* g, u16* l) {
  __builtin_amdgcn_global_load_lds(
      (const __attribute__((address_space(1))) unsigned int*)g,
      (__attribute__((address_space(3))) unsigned int*)l, 16, 0, 0);
}

// ---------------------------------------------------------------------------
// fp32 -> bf16 for the 5 matrix inputs.
// ---------------------------------------------------------------------------
struct Cvt5 {
  const float* src[5];
  unsigned cnt4[5];  // quads per segment
  unsigned ooff[5];  // out offset (u16 elements)
};

__global__ __launch_bounds__(256)
void cvt5_kernel(Cvt5 a, u16* __restrict__ out, unsigned total4)
{
  unsigned gid = blockIdx.x * 256u + threadIdx.x;
  if (gid >= total4) return;
  unsigned rem = gid;
  int s = 0;
  while (s < 4 && rem >= a.cnt4[s]) { rem -= a.cnt4[s]; ++s; }
  const float4 v = ((const float4*)a.src[s])[rem];
  ushort4 o;
  o.x = f2bf(v.x); o.y = f2bf(v.y); o.z = f2bf(v.z); o.w = f2bf(v.w);
  *(ushort4*)(out + a.ooff[s] + (size_t)rem * 4) = o;
}

// ---------------------------------------------------------------------------
// C[m,n] = (sum_k A[m,k] B[n,k] + bias[n]) * rowscale[m]   (all-bf16 inputs)
// A split: k<splitK from A0 (row stride splitK), else A1 (stride K-splitK).
// m97 structure: 128x128 tile, BK=32, global_load_lds w=16, 2x2 waves x 4x4.
// MFMA conventions (HW-verified): A-frag A[l%16][8*(l/16)+j],
// B-frag B[n=l%16][k=8*(l/16)+j], D row=4*(l/16)+r col=l%16.
// ---------------------------------------------------------------------------
template <typename OutT>
__global__ __launch_bounds__(256, 2)
void gemm_bt_kernel(const u16* __restrict__ A0, const u16* __restrict__ A1,
                    int splitK,
                    const u16* __restrict__ Bw, const float* __restrict__ bias,
                    const float* __restrict__ rowscale,
                    OutT* __restrict__ C, int N, int K)
{
  __shared__ u16 As[128 * 32];
  __shared__ u16 Bs[128 * 32];
  const int tid  = threadIdx.x;
  const int lane = tid & 63;
  const int w    = tid >> 6;
  const int wm = w >> 1, wn = w & 1;
  const int quad = lane >> 4, lr = lane & 15;
  const int m0 = blockIdx.y * 128;
  const int n0 = blockIdx.x * 128;

  const f32x4 z4 = {0.f, 0.f, 0.f, 0.f};
  f32x4 acc[4][4];
#pragma unroll
  for (int i = 0; i < 4; ++i)
#pragma unroll
    for (int j = 0; j < 4; ++j)
      acc[i][j] = z4;

  const int acol = (tid & 3) * 8;  // k-offset of this thread's 16B chunk

  for (int k0 = 0; k0 < K; k0 += 32) {
    const u16* Ap; int lda, kk;
    if (k0 < splitK) { Ap = A0; lda = splitK;     kk = k0; }
    else             { Ap = A1; lda = K - splitK; kk = k0 - splitK; }
    __syncthreads();  // previous tile's reads done before overwrite
#pragma unroll
    for (int it = 0; it < 2; ++it) {
      const int row = it * 64 + (tid >> 2);
      const int ldsbase = (it * 256 + (tid & 192)) * 8;  // wave-uniform chunk base
      async16(Ap + (size_t)(m0 + row) * lda + (kk + acol), &As[ldsbase]);
      async16(Bw + (size_t)(n0 + row) * K   + (k0 + acol), &Bs[ldsbase]);
    }
    __syncthreads();  // staging visible

    bf16x8 af[4], bfr[4];
#pragma unroll
    for (int i = 0; i < 4; ++i)
      af[i] = *(const bf16x8*)&As[(wm * 64 + i * 16 + lr) * 32 + quad * 8];
#pragma unroll
    for (int j = 0; j < 4; ++j)
      bfr[j] = *(const bf16x8*)&Bs[(wn * 64 + j * 16 + lr) * 32 + quad * 8];
#pragma unroll
    for (int i = 0; i < 4; ++i)
#pragma unroll
      for (int j = 0; j < 4; ++j)
        acc[i][j] = MFMA16(af[i], bfr[j], acc[i][j]);
  }

  float bv[4];
#pragma unroll
  for (int j = 0; j < 4; ++j)
    bv[j] = bias[n0 + wn * 64 + j * 16 + lr];

#pragma unroll
  for (int i = 0; i < 4; ++i)
#pragma unroll
    for (int r = 0; r < 4; ++r) {
      const int grow = m0 + wm * 64 + i * 16 + quad * 4 + r;
      float rs = 1.f;
      if (rowscale) rs = rowscale[grow];
#pragma unroll
      for (int j = 0; j < 4; ++j) {
        const int gcol = n0 + wn * 64 + j * 16 + lr;
        store_out(&C[(size_t)grow * N + gcol], (acc[i][j][r] + bv[j]) * rs);
      }
    }
}

// ---------------------------------------------------------------------------
// MFMA flash attention (unchanged from passing round 6).
// ---------------------------------------------------------------------------
#define SCLOG2E 0.12751813754618667f  // (1/sqrt(128)) * log2(e)

__global__ __launch_bounds__(256, 2)
void flash_kernel(const u16* __restrict__ q, const u16* __restrict__ kv,
                  const float* __restrict__ smask, u16* __restrict__ upd)
{
  __shared__ u16 Ks[64 * 128];    // 16 KB
  __shared__ u16 Vt[128 * 72];    // 18 KB
  __shared__ u16 Ps[4][32 * 72];  // 18 KB

  const int tid  = threadIdx.x;
  const int lane = tid & 63;
  const int w    = tid >> 6;
  const int quad = lane >> 4, lr = lane & 15;
  const int b = blockIdx.z, h = blockIdx.y, qt = blockIdx.x;

  const size_t qrow0 = (size_t)b * 1024 + qt * 128 + w * 32;

  bf16x8 qf[2][4];  // A-layout: m=lane&15, k=quad*8+j
#pragma unroll
  for (int i = 0; i < 2; ++i)
#pragma unroll
    for (int kk = 0; kk < 4; ++kk)
      qf[i][kk] = *(const bf16x8*)&q[(qrow0 + i * 16 + lr) * 1024 + h * 128 + kk * 32 + quad * 8];

  const f32x4 z4 = {0.f, 0.f, 0.f, 0.f};
  f32x4 oacc[2][8];
#pragma unroll
  for (int i = 0; i < 2; ++i)
#pragma unroll
    for (int jd = 0; jd < 8; ++jd)
      oacc[i][jd] = z4;
  float mrun[2][4], lrun[2][4];
#pragma unroll
  for (int i = 0; i < 2; ++i)
#pragma unroll
    for (int r = 0; r < 4; ++r) { mrun[i][r] = -1e30f; lrun[i][r] = 0.f; }

  for (int s0 = 0; s0 < 1024; s0 += 64) {
    __syncthreads();
#pragma unroll
    for (int it = 0; it < 4; ++it) {
      const int f = it * 256 + tid;
      const int srow = f & 63, dc = f >> 6;
      async16(kv + ((size_t)b * 1024 + s0 + srow) * 2048 + h * 128 + dc * 8,
              &Ks[(it * 256 + (tid & 192)) * 8]);
    }
#pragma unroll
    for (int it = 0; it < 4; ++it) {
      const int f = it * 256 + tid;
      const int srow = f & 63, dc = f >> 6;
      u16x8 vv = *(const u16x8*)(kv + ((size_t)b * 1024 + s0 + srow) * 2048 + 1024 + h * 128 + dc * 8);
#pragma unroll
      for (int jj = 0; jj < 8; ++jj)
        Vt[(dc * 8 + jj) * 72 + srow] = vv[jj];
    }
    __syncthreads();

    f32x4 sacc[2][4];
#pragma unroll
    for (int i = 0; i < 2; ++i)
#pragma unroll
      for (int j = 0; j < 4; ++j)
        sacc[i][j] = z4;
#pragma unroll
    for (int kk = 0; kk < 4; ++kk) {
      bf16x8 kb[4];
#pragma unroll
      for (int j = 0; j < 4; ++j)
        kb[j] = *(const bf16x8*)&Ks[((kk * 4 + quad) * 64 + j * 16 + lr) * 8];
#pragma unroll
      for (int i = 0; i < 2; ++i)
#pragma unroll
        for (int j = 0; j < 4; ++j)
          sacc[i][j] = MFMA16(qf[i][kk], kb[j], sacc[i][j]);
    }

    float mb[4];
#pragma unroll
    for (int j = 0; j < 4; ++j) {
      const float mv = smask[b * 1024 + s0 + j * 16 + lr];
      mb[j] = (mv == 0.f) ? -1e30f : 0.f;
    }

#pragma unroll
    for (int i = 0; i < 2; ++i) {
      float alpha[4];
#pragma unroll
      for (int r = 0; r < 4; ++r) {
        float e[4];
#pragma unroll
        for (int j = 0; j < 4; ++j)
          e[j] = sacc[i][j][r] * SCLOG2E + mb[j];
        float vm = fmaxf(fmaxf(e[0], e[1]), fmaxf(e[2], e[3]));
        vm = fmaxf(vm, __shfl_xor(vm, 1));
        vm = fmaxf(vm, __shfl_xor(vm, 2));
        vm = fmaxf(vm, __shfl_xor(vm, 4));
        vm = fmaxf(vm, __shfl_xor(vm, 8));
        const float mnew = fmaxf(mrun[i][r], vm);
        alpha[r] = exp2f(mrun[i][r] - mnew);
        mrun[i][r] = mnew;
        float ps = 0.f;
#pragma unroll
        for (int j = 0; j < 4; ++j) {
          float p = exp2f(e[j] - mnew);
          ps += p;
          Ps[w][(i * 16 + quad * 4 + r) * 72 + j * 16 + lr] = f2bf(p);
        }
        ps += __shfl_xor(ps, 1);
        ps += __shfl_xor(ps, 2);
        ps += __shfl_xor(ps, 4);
        ps += __shfl_xor(ps, 8);
        lrun[i][r] = lrun[i][r] * alpha[r] + ps;
      }
#pragma unroll
      for (int jd = 0; jd < 8; ++jd)
#pragma unroll
        for (int r = 0; r < 4; ++r)
          oacc[i][jd][r] *= alpha[r];
    }

#pragma unroll
    for (int kk2 = 0; kk2 < 2; ++kk2) {
      bf16x8 pa[2], vb[8];
#pragma unroll
      for (int i = 0; i < 2; ++i)
        pa[i] = *(const bf16x8*)&Ps[w][(i * 16 + lr) * 72 + kk2 * 32 + quad * 8];
#pragma unroll
      for (int jd = 0; jd < 8; ++jd)
        vb[jd] = *(const bf16x8*)&Vt[(jd * 16 + lr) * 72 + kk2 * 32 + quad * 8];
#pragma unroll
      for (int i = 0; i < 2; ++i)
#pragma unroll
        for (int jd = 0; jd < 8; ++jd)
          oacc[i][jd] = MFMA16(pa[i], vb[jd], oacc[i][jd]);
    }
  }

#pragma unroll
  for (int i = 0; i < 2; ++i)
#pragma unroll
    for (int r = 0; r < 4; ++r) {
      const float inv = 1.f / lrun[i][r];
      const size_t grow = qrow0 + i * 16 + quad * 4 + r;
#pragma unroll
      for (int jd = 0; jd < 8; ++jd)
        upd[grow * 1024 + h * 128 + jd * 16 + lr] = f2bf(oacc[i][jd][r] * inv);
    }
}

// diagnostic: mark out[0] with a magic value (fp32 -> observable)
__global__ void magic_kernel(float* out, float val)
{
  if (threadIdx.x == 0 && blockIdx.x == 0) out[0] = val;
}

// ---------------------------------------------------------------------------
extern "C" void kernel_launch(void* const* d_in, const int* in_sizes, int n_in,
                              void* d_out, int out_size, void* d_ws, size_t ws_size,
                              hipStream_t stream)
{
  static const int dict_sz[10]   = {8388608, 8388608, 8192, 8192, 2097152,
                                    2048, 1048576, 1024, 2097152, 1024};
  static const int sorted_sz[10] = {2097152, 2097152, 1048576, 1024, 2048,
                                    1024, 8388608, 8192, 8388608, 8192};
  bool is_dict = (n_in == 10), is_sorted = (n_in == 10);
  if (n_in == 10) {
    for (int i = 0; i < 10; ++i) {
      if (in_sizes[i] != dict_sz[i])   is_dict = false;
      if (in_sizes[i] != sorted_sz[i]) is_sorted = false;
    }
  }

  const float *src, *tgt, *smask, *tmask, *Ws, *bs, *Wt, *bt, *Wo, *bo;
  if (is_sorted) {  // [Wo, Ws, Wt, bo, bs, bt, src, src_mask, tgt, tgt_mask]
    Wo    = (const float*)d_in[0];
    Ws    = (const float*)d_in[1];
    Wt    = (const float*)d_in[2];
    bo    = (const float*)d_in[3];
    bs    = (const float*)d_in[4];
    bt    = (const float*)d_in[5];
    src   = (const float*)d_in[6];
    smask = (const float*)d_in[7];
    tgt   = (const float*)d_in[8];
    tmask = (const float*)d_in[9];
  } else {  // dict order (documented contract)
    src   = (const float*)d_in[0];
    tgt   = (const float*)d_in[1];
    smask = (const float*)d_in[2];
    tmask = (const float*)d_in[3];
    Ws    = (const float*)d_in[4];
    bs    = (const float*)d_in[5];
    Wt    = (const float*)d_in[6];
    bt    = (const float*)d_in[7];
    Wo    = (const float*)d_in[8];
    bo    = (const float*)d_in[9];
  }
  float* out = (float*)d_out;  // fp32 output

  // ws layout (u16 elements)
  const size_t KV = 16777216, Q = 8388608, UPD = 8388608;
  const unsigned segsz[5] = {8388608u, 8388608u, 2097152u, 1048576u, 2097152u};
  // arena: src, tgt, Ws, Wt, Wo
  size_t total_u16 = KV + Q + UPD;
  unsigned aoff[5], off = 0, total4 = 0;
  for (int i = 0; i < 5; ++i) {
    aoff[i] = off;
    off += segsz[i];
    total4 += segsz[i] / 4u;
  }
  total_u16 += off;

  unsigned ws_mb = (unsigned)(ws_size >> 20);
  if (ws_mb > 999u) ws_mb = 999u;
  if (!is_dict && !is_sorted) {
    magic_kernel<<<dim3(1), dim3(64), 0, stream>>>(out, 4000.f + (float)ws_mb);
    return;
  }
  if (ws_size < total_u16 * 2) {
    magic_kernel<<<dim3(1), dim3(64), 0, stream>>>(out, 3000.f + (float)ws_mb);
    return;
  }

  u16* kvbuf  = (u16*)d_ws;
  u16* qbuf   = kvbuf + KV;
  u16* updbuf = qbuf + Q;
  u16* arena  = updbuf + UPD;

  Cvt5 ca;
  const float* segp[5] = {src, tgt, Ws, Wt, Wo};
  for (int i = 0; i < 5; ++i) {
    ca.src[i]  = segp[i];
    ca.cnt4[i] = segsz[i] / 4u;
    ca.ooff[i] = aoff[i];
  }
  const u16* srcb = arena + aoff[0];
  const u16* tgtb = arena + aoff[1];
  const u16* Wsb  = arena + aoff[2];
  const u16* Wtb  = arena + aoff[3];
  const u16* Wob  = arena + aoff[4];

  dim3 blk(256);
  // CVT: fp32 -> bf16 arena
  cvt5_kernel<<<dim3((total4 + 255u) / 256u), blk, 0, stream>>>(ca, arena, total4);
  // GEMM1: kv = (src @ Ws^T + bs) * src_mask   (bf16 ws output)
  gemm_bt_kernel<u16><<<dim3(16, 64), blk, 0, stream>>>(
      srcb, nullptr, 1024, Wsb, bs, smask, kvbuf, 2048, 1024);
  // GEMM2: q = (tgt @ Wt^T + bt) * tgt_mask    (bf16 ws output)
  gemm_bt_kernel<u16><<<dim3(8, 64), blk, 0, stream>>>(
      tgtb, nullptr, 1024, Wtb, bt, tmask, qbuf, 1024, 1024);
  // FLASH (MFMA): upd = softmax(q k^T) v       (bf16 ws output)
  flash_kernel<<<dim3(8, 8, 8), blk, 0, stream>>>(qbuf, kvbuf, smask, updbuf);
  // GEMM3: out = [tgt | upd] @ Wo^T + bo       (fp32 output)
  gemm_bt_kernel<float><<<dim3(8, 64), blk, 0, stream>>>(
      tgtb, updbuf, 1024, Wob, bo, nullptr, out, 1024, 2048);
}